// Round 2
// baseline (391.936 us; speedup 1.0000x reference)
//
#include <hip/hip_runtime.h>
#include <hip/hip_bf16.h>

// Problem constants (from reference):
//   B=64, C=256, H=W=56  -> HW=3136 (=784 float4), SQ=64
//   x: [B,C,H,W] f32; w1: [SQ,C]; b1: [SQ]; w2: [C,SQ]; b2: [C]
#define SE_B   64
#define SE_C   256
#define SE_SQ  64
#define SE_HW  3136
#define SE_HW4 784   // float4s per plane
#define SE_PLANES (SE_B * SE_C)   // 16384

// ---------------------------------------------------------------------------
// Kernel 1: global average pool. ONE WAVE per (b,c) plane — no barrier, no
// cross-wave LDS. 4 waves/block -> 4 consecutive planes/block (50 KB
// contiguous per block). 784 float4 / 64 lanes = 12 iters (+1 for lanes<16).
// ---------------------------------------------------------------------------
__global__ __launch_bounds__(256) void se_pool(const float* __restrict__ x,
                                               float* __restrict__ s) {
    const int plane = (blockIdx.x << 2) + (threadIdx.x >> 6);  // 4 planes/block
    const int lane  = threadIdx.x & 63;
    const float4* xp = (const float4*)(x + (size_t)plane * SE_HW);

    float sum = 0.0f;
    #pragma unroll
    for (int it = 0; it < 12; ++it) {
        float4 v = xp[lane + it * 64];
        sum += (v.x + v.y) + (v.z + v.w);
    }
    if (lane < 16) {                       // 784 = 12*64 + 16 tail
        float4 v = xp[lane + 768];
        sum += (v.x + v.y) + (v.z + v.w);
    }

    #pragma unroll
    for (int off = 32; off > 0; off >>= 1)
        sum += __shfl_down(sum, off, 64);

    if (lane == 0) s[plane] = sum * (1.0f / (float)SE_HW);
}

// ---------------------------------------------------------------------------
// Kernel 2: excitation MLP. One block per batch (64 blocks, 256 threads).
//   h = relu(w1 @ s_b + b1)   [SQ]
//   g = sigmoid(w2 @ h + b2)  [C]
// ~4 MFLOP across the grid — latency-bound noise. float4 dot loops.
// ---------------------------------------------------------------------------
__global__ __launch_bounds__(256) void se_fc(const float* __restrict__ s,
                                             const float* __restrict__ w1,
                                             const float* __restrict__ b1,
                                             const float* __restrict__ w2,
                                             const float* __restrict__ b2,
                                             float* __restrict__ g) {
    const int b = blockIdx.x;
    __shared__ float s_sh[SE_C];
    __shared__ float h_sh[SE_SQ];

    s_sh[threadIdx.x] = s[b * SE_C + threadIdx.x];
    __syncthreads();

    if (threadIdx.x < SE_SQ) {
        float acc = b1[threadIdx.x];
        const float4* w = (const float4*)(w1 + (size_t)threadIdx.x * SE_C);
        const float4* ss = (const float4*)s_sh;
        #pragma unroll 8
        for (int c = 0; c < SE_C / 4; ++c) {
            float4 wv = w[c], sv = ss[c];
            acc = fmaf(wv.x, sv.x, acc);
            acc = fmaf(wv.y, sv.y, acc);
            acc = fmaf(wv.z, sv.z, acc);
            acc = fmaf(wv.w, sv.w, acc);
        }
        h_sh[threadIdx.x] = fmaxf(acc, 0.0f);
    }
    __syncthreads();

    float acc = b2[threadIdx.x];
    const float4* w = (const float4*)(w2 + (size_t)threadIdx.x * SE_SQ);
    const float4* hh = (const float4*)h_sh;
    #pragma unroll
    for (int k = 0; k < SE_SQ / 4; ++k) {
        float4 wv = w[k], hv = hh[k];
        acc = fmaf(wv.x, hv.x, acc);
        acc = fmaf(wv.y, hv.y, acc);
        acc = fmaf(wv.z, hv.z, acc);
        acc = fmaf(wv.w, hv.w, acc);
    }
    g[b * SE_C + threadIdx.x] = 1.0f / (1.0f + __expf(-acc));
}

// ---------------------------------------------------------------------------
// Kernel 3: broadcast scale. ONE WAVE per plane, 4 planes/block, no barrier.
// 12-13 independent float4 load/store pairs per lane for ILP.
// ---------------------------------------------------------------------------
__global__ __launch_bounds__(256) void se_scale(const float* __restrict__ x,
                                                const float* __restrict__ g,
                                                float* __restrict__ out) {
    const int plane = (blockIdx.x << 2) + (threadIdx.x >> 6);
    const int lane  = threadIdx.x & 63;
    const float gv  = g[plane];
    const float4* xp = (const float4*)(x + (size_t)plane * SE_HW);
    float4* op = (float4*)(out + (size_t)plane * SE_HW);

    #pragma unroll
    for (int it = 0; it < 12; ++it) {
        float4 v = xp[lane + it * 64];
        v.x *= gv; v.y *= gv; v.z *= gv; v.w *= gv;
        op[lane + it * 64] = v;
    }
    if (lane < 16) {
        float4 v = xp[lane + 768];
        v.x *= gv; v.y *= gv; v.z *= gv; v.w *= gv;
        op[lane + 768] = v;
    }
}

extern "C" void kernel_launch(void* const* d_in, const int* in_sizes, int n_in,
                              void* d_out, int out_size, void* d_ws, size_t ws_size,
                              hipStream_t stream) {
    const float* x  = (const float*)d_in[0];
    const float* w1 = (const float*)d_in[1];
    const float* b1 = (const float*)d_in[2];
    const float* w2 = (const float*)d_in[3];
    const float* b2 = (const float*)d_in[4];
    float* out = (float*)d_out;

    // workspace: s[B*C] then g[B*C] — fully overwritten before read each call
    float* s = (float*)d_ws;
    float* g = s + SE_PLANES;

    se_pool <<<SE_PLANES / 4, 256, 0, stream>>>(x, s);
    se_fc   <<<SE_B,          256, 0, stream>>>(s, w1, b1, w2, b2, g);
    se_scale<<<SE_PLANES / 4, 256, 0, stream>>>(x, g, out);
}